// Round 4
// baseline (694.782 us; speedup 1.0000x reference)
//
#include <hip/hip_runtime.h>
#include <cstdint>
#include <cstddef>

#define BB 2
#define SS 2048
#define EE 1024
#define HH 16
#define DH 64
#define KKSEL 409   // kk = int(2048*0.2)
#define QT 16       // query rows per attention block
#define PST 136     // probs LDS row stride (bf16 elems) per half (128 cols + pad)

typedef __attribute__((ext_vector_type(8))) short bf16x8;
typedef __attribute__((ext_vector_type(4))) float f32x4;
typedef unsigned short ushort_t;

__device__ __forceinline__ unsigned short f2bf(float f){
    unsigned u = __float_as_uint(f);
    u += 0x7fffu + ((u >> 16) & 1u);          // RNE
    return (unsigned short)(u >> 16);
}
__device__ __forceinline__ float bf2f(unsigned short h){
    return __uint_as_float(((unsigned)h) << 16);
}
__device__ __forceinline__ unsigned sortkey(float f){
    unsigned u = __float_as_uint(f);
    return (u & 0x80000000u) ? ~u : (u | 0x80000000u);
}
__device__ __forceinline__ float inv_sortkey(unsigned k){
    unsigned u = (k & 0x80000000u) ? (k & 0x7fffffffu) : ~k;
    return __uint_as_float(u);
}
__device__ __forceinline__ void split8(const float* f, bf16x8& h, bf16x8& l){
    #pragma unroll
    for (int j = 0; j < 8; ++j){
        ushort_t hh = f2bf(f[j]);
        h[j] = (short)hh;
        l[j] = (short)f2bf(f[j] - bf2f(hh));
    }
}
// async 16B/lane global->LDS; LDS dest = wave-uniform base + lane*16
__device__ __forceinline__ void gload_lds16(const ushort_t* g, ushort_t* l){
    __builtin_amdgcn_global_load_lds(
        (const __attribute__((address_space(1))) void*)g,
        (__attribute__((address_space(3))) void*)l, 16, 0, 0);
}

__device__ __forceinline__ void wave_minmax(const float* cand, float& mn, float& mx){
    mx = cand[0]; mn = cand[0];
    #pragma unroll
    for (int j = 1; j < 32; ++j){
        mx = fmaxf(mx, cand[j]);
        mn = fminf(mn, cand[j]);
    }
    #pragma unroll
    for (int off = 1; off < 64; off <<= 1){
        mx = fmaxf(mx, __shfl_xor(mx, off, 64));
        mn = fminf(mn, __shfl_xor(mn, off, 64));
    }
}
// Binary key-space bisection; counts via ballot. Invariant: cnt(lo) >= K,
// cnt(hi) < K. Early exit when a mid separates exactly K. DS-free.
__device__ __forceinline__ float bisect_thresh(const float* cand, float mn, float mx){
    unsigned lo = sortkey(mn), hi = sortkey(mx) + 1u;
    #pragma unroll 1
    for (int it = 0; it < 32 && (hi - lo) > 1u; ++it){
        const unsigned mid = lo + ((hi - lo) >> 1);
        const float midf = inv_sortkey(mid);
        int c = 0;
        #pragma unroll
        for (int j = 0; j < 32; ++j)
            c += (int)__popcll(__ballot(cand[j] >= midf));
        if (c == KKSEL){ lo = mid; break; }
        if (c > KKSEL) lo = mid; else hi = mid;
    }
    return inv_sortkey(lo);
}

// ---------------------------------------------------------------------------
// convert_wt4: 4x fused. W (1024x1024 [k][n]) -> W^T bf16 hi/lo ([n][k])
// ---------------------------------------------------------------------------
struct CvtArgs {
    const float* W[4];
    ushort_t* H[4];
    ushort_t* L[4];
};

__global__ __launch_bounds__(256) void convert_wt4(CvtArgs a)
{
    __shared__ float T[64][65];
    const int z = blockIdx.z;
    const float* __restrict__ W = a.W[z];
    ushort_t* __restrict__ Ht = a.H[z];
    ushort_t* __restrict__ Lt = a.L[z];

    const int tid = threadIdx.x;
    const int ty = tid >> 4, tx = tid & 15;
    const int n0 = blockIdx.x * 64, k0 = blockIdx.y * 64;
    #pragma unroll
    for (int i = 0; i < 4; ++i){
        const int kl = ty + i * 16;
        float4 w = *(const float4*)&W[(size_t)(k0 + kl) * EE + n0 + tx * 4];
        T[kl][tx*4 + 0] = w.x; T[kl][tx*4 + 1] = w.y;
        T[kl][tx*4 + 2] = w.z; T[kl][tx*4 + 3] = w.w;
    }
    __syncthreads();
    #pragma unroll
    for (int i = 0; i < 4; ++i){
        const int nl = ty + i * 16;
        ushort4 h, l;
        ushort_t* hp = &h.x; ushort_t* lp = &l.x;
        #pragma unroll
        for (int j = 0; j < 4; ++j){
            const float v = T[tx*4 + j][nl];
            ushort_t hh = f2bf(v);
            hp[j] = hh;
            lp[j] = f2bf(v - bf2f(hh));
        }
        const size_t o = (size_t)(n0 + nl) * EE + k0 + tx * 4;
        *(ushort4*)&Ht[o] = h;
        *(ushort4*)&Lt[o] = l;
    }
}

// ---------------------------------------------------------------------------
// convert_x3: activations (4096x1024 fp32) -> split bf16 hi/lo, row-major.
// Pure BW-bound; hoists the fp32->split conversion out of the GEMM k-loops
// (was re-done 8x per element, ~half of GEMM time).
// ---------------------------------------------------------------------------
struct CvtX {
    const float* X[3];
    ushort_t* H[3];
    ushort_t* L[3];
};

__global__ __launch_bounds__(256) void convert_x3(CvtX a)
{
    const int z = blockIdx.z;
    const float* __restrict__ X = a.X[z];
    ushort_t* __restrict__ Hd = a.H[z];
    ushort_t* __restrict__ Ld = a.L[z];
    const size_t i = ((size_t)blockIdx.x * 256 + threadIdx.x) * 8;
    float fx[8];
    *(float4*)&fx[0] = *(const float4*)&X[i];
    *(float4*)&fx[4] = *(const float4*)&X[i + 4];
    bf16x8 h, l;
    split8(fx, h, l);
    *(bf16x8*)&Hd[i] = h;
    *(bf16x8*)&Ld[i] = l;
}

// ---------------------------------------------------------------------------
// Split-bf16 MFMA GEMM body, all operands pre-split bf16 hi/lo in global.
// Both A (X) and B (W^T) staged via async global_load_lds (16B/lane, linear
// LDS). k-loop has zero conversion VALU. buf = 2 stages x 32 KB.
// MODE 0: Q -> bf16 hi/lo [bh][s][d], pre-scaled by 0.15625 (fused score scale)
// MODE 1: K -> hi, scaled by ts[h]
// MODE 2: V -> hi, transposed [bh][d][s]   MODE 3: fp32 row-major
// ---------------------------------------------------------------------------
template<int MODE>
__device__ __forceinline__ void gemm_body(
        const ushort_t* __restrict__ Xh, const ushort_t* __restrict__ Xl,
        const ushort_t* __restrict__ Wth, const ushort_t* __restrict__ Wtl,
        const float* __restrict__ bias, const float* __restrict__ ts,
        float* __restrict__ OutF, ushort_t* __restrict__ OutH,
        ushort_t* __restrict__ OutL, ushort_t* buf)
{
    const int tid  = threadIdx.x;
    const int lane = tid & 63, wave = tid >> 6;
    const int c16  = lane & 15, qd = lane >> 4;
    const int m0 = blockIdx.y * 128, n0 = blockIdx.x * 128;
    const int wm = (wave >> 1) * 64, wn = (wave & 1) * 64;

    f32x4 acc[4][4];
    #pragma unroll
    for (int a = 0; a < 4; ++a)
        #pragma unroll
        for (int b = 0; b < 4; ++b) acc[a][b] = (f32x4){0.f,0.f,0.f,0.f};

    // staging: each wave owns segments seg0/seg1 (16 rows each) of the
    // 128-row tile; lane covers row seg*16 + lane/4, k (lane&3)*8.
    const int seg0 = wave * 2, seg1 = seg0 + 1;
    const int rl = lane >> 2, kl = (lane & 3) * 8;
    const size_t aofs0 = (size_t)(m0 + seg0*16 + rl) * EE + kl;
    const size_t aofs1 = (size_t)(m0 + seg1*16 + rl) * EE + kl;
    const size_t bofs0 = (size_t)(n0 + seg0*16 + rl) * EE + kl;
    const size_t bofs1 = (size_t)(n0 + seg1*16 + rl) * EE + kl;

    auto stage = [&](ushort_t* S, int kt){
        gload_lds16(Xh  + aofs0 + kt, S +         seg0*512);
        gload_lds16(Xh  + aofs1 + kt, S +         seg1*512);
        gload_lds16(Xl  + aofs0 + kt, S + 4096  + seg0*512);
        gload_lds16(Xl  + aofs1 + kt, S + 4096  + seg1*512);
        gload_lds16(Wth + bofs0 + kt, S + 8192  + seg0*512);
        gload_lds16(Wth + bofs1 + kt, S + 8192  + seg1*512);
        gload_lds16(Wtl + bofs0 + kt, S + 12288 + seg0*512);
        gload_lds16(Wtl + bofs1 + kt, S + 12288 + seg1*512);
    };

    stage(buf, 0);
    __syncthreads();

    int cur = 0;
    for (int k0 = 0; k0 < EE; k0 += 32){
        const bool more = (k0 + 32) < EE;
        if (more) stage(buf + (cur ^ 1) * 16384, k0 + 32);
        const ushort_t* S  = buf + cur * 16384;
        const ushort_t* A0 = S;
        const ushort_t* A1 = S + 4096;
        const ushort_t* B0 = S + 8192;
        const ushort_t* B1 = S + 12288;
        bf16x8 afh[4], afl[4], bfh[4], bfl[4];
        #pragma unroll
        for (int i = 0; i < 4; ++i){
            afh[i] = *(const bf16x8*)&A0[(wm + i*16 + c16)*32 + qd*8];
            afl[i] = *(const bf16x8*)&A1[(wm + i*16 + c16)*32 + qd*8];
            bfh[i] = *(const bf16x8*)&B0[(wn + i*16 + c16)*32 + qd*8];
            bfl[i] = *(const bf16x8*)&B1[(wn + i*16 + c16)*32 + qd*8];
        }
        #pragma unroll
        for (int a = 0; a < 4; ++a){
            #pragma unroll
            for (int b = 0; b < 4; ++b){
                if (MODE == 2){   // X first: D rows <- s
                    acc[a][b] = __builtin_amdgcn_mfma_f32_16x16x32_bf16(afh[a], bfh[b], acc[a][b], 0,0,0);
                    acc[a][b] = __builtin_amdgcn_mfma_f32_16x16x32_bf16(afh[a], bfl[b], acc[a][b], 0,0,0);
                    acc[a][b] = __builtin_amdgcn_mfma_f32_16x16x32_bf16(afl[a], bfh[b], acc[a][b], 0,0,0);
                } else {          // W first: D rows <- n
                    acc[a][b] = __builtin_amdgcn_mfma_f32_16x16x32_bf16(bfh[a], afh[b], acc[a][b], 0,0,0);
                    acc[a][b] = __builtin_amdgcn_mfma_f32_16x16x32_bf16(bfh[a], afl[b], acc[a][b], 0,0,0);
                    acc[a][b] = __builtin_amdgcn_mfma_f32_16x16x32_bf16(bfl[a], afh[b], acc[a][b], 0,0,0);
                }
            }
        }
        if (more){
            __syncthreads();   // drains vmcnt (async stages) + wave sync
            cur ^= 1;
        }
    }

    if (MODE == 3){
        #pragma unroll
        for (int a = 0; a < 4; ++a){
            const int ng = n0 + wn + a*16 + qd*4;
            float4 b4 = *(const float4*)&bias[ng];
            const float bb[4] = {b4.x, b4.y, b4.z, b4.w};
            #pragma unroll
            for (int b = 0; b < 4; ++b){
                const int mg = m0 + wm + b*16 + c16;
                float4 o;
                o.x = acc[a][b][0] + bb[0]; o.y = acc[a][b][1] + bb[1];
                o.z = acc[a][b][2] + bb[2]; o.w = acc[a][b][3] + bb[3];
                *(float4*)&OutF[(size_t)mg * EE + ng] = o;
            }
        }
    } else if (MODE == 0){
        #pragma unroll
        for (int a = 0; a < 4; ++a){
            const int ng = n0 + wn + a*16 + qd*4;
            const int h = ng >> 6, d0 = ng & 63;
            float4 b4 = *(const float4*)&bias[ng];
            const float bb[4] = {b4.x, b4.y, b4.z, b4.w};
            #pragma unroll
            for (int b = 0; b < 4; ++b){
                const int mg = m0 + wm + b*16 + c16;
                const int bi = mg >> 11, s = mg & (SS - 1);
                ushort4 hv, lv;
                ushort_t* hp = &hv.x; ushort_t* lp = &lv.x;
                #pragma unroll
                for (int r = 0; r < 4; ++r){
                    // fused score scale: 1/8 * 1.25 folded into Q
                    const float v = (acc[a][b][r] + bb[r]) * 0.15625f;
                    ushort_t hh = f2bf(v);
                    hp[r] = hh;
                    lp[r] = f2bf(v - bf2f(hh));
                }
                const size_t o = (((size_t)(bi * HH + h)) * SS + s) * DH + d0;
                *(ushort4*)&OutH[o] = hv;
                *(ushort4*)&OutL[o] = lv;
            }
        }
    } else if (MODE == 1){
        #pragma unroll
        for (int a = 0; a < 4; ++a){
            const int ng = n0 + wn + a*16 + qd*4;
            const int h = ng >> 6, d0 = ng & 63;
            const float tsc = ts[h];
            float4 b4 = *(const float4*)&bias[ng];
            const float bb[4] = {b4.x, b4.y, b4.z, b4.w};
            #pragma unroll
            for (int b = 0; b < 4; ++b){
                const int mg = m0 + wm + b*16 + c16;
                const int bi = mg >> 11, s = mg & (SS - 1);
                ushort4 hv;
                ushort_t* hp = &hv.x;
                #pragma unroll
                for (int r = 0; r < 4; ++r)
                    hp[r] = f2bf((acc[a][b][r] + bb[r]) * tsc);
                *(ushort4*)&OutH[(((size_t)(bi * HH + h)) * SS + s) * DH + d0] = hv;
            }
        }
    } else { // MODE 2: V^T hi only
        #pragma unroll
        for (int a = 0; a < 4; ++a){
            const int mg = m0 + wm + a*16 + qd*4;
            const int bi = mg >> 11, s0 = mg & (SS - 1);
            #pragma unroll
            for (int b = 0; b < 4; ++b){
                const int ng = n0 + wn + b*16 + c16;
                const int h = ng >> 6, d = ng & 63;
                const float bv = bias[ng];
                ushort4 hv;
                ushort_t* hp = &hv.x;
                #pragma unroll
                for (int r = 0; r < 4; ++r) hp[r] = f2bf(acc[a][b][r] + bv);
                *(ushort4*)&OutH[(((size_t)(bi * HH + h)) * DH + d) * SS + s0] = hv;
            }
        }
    }
}

// Fused Q/K/V projections: blockIdx.z picks the problem.
__global__ __launch_bounds__(256) void gemm_qkv(
        const ushort_t* __restrict__ Xqh, const ushort_t* __restrict__ Xql,
        const ushort_t* __restrict__ Xkh, const ushort_t* __restrict__ Xkl,
        const ushort_t* __restrict__ Xvh, const ushort_t* __restrict__ Xvl,
        const ushort_t* __restrict__ Wqh, const ushort_t* __restrict__ Wql,
        const ushort_t* __restrict__ Wkh, const ushort_t* __restrict__ Wkl,
        const ushort_t* __restrict__ Wvh, const ushort_t* __restrict__ Wvl,
        const float* __restrict__ bq, const float* __restrict__ bk,
        const float* __restrict__ bv, const float* __restrict__ ts,
        ushort_t* __restrict__ Qh, ushort_t* __restrict__ Ql,
        ushort_t* __restrict__ Kh, ushort_t* __restrict__ Vth)
{
    __shared__ ushort_t buf[2 * 16384];
    const int z = blockIdx.z;
    if (z == 0)
        gemm_body<0>(Xqh, Xql, Wqh, Wql, bq, nullptr, nullptr, Qh, Ql, buf);
    else if (z == 1)
        gemm_body<1>(Xkh, Xkl, Wkh, Wkl, bk, ts, nullptr, Kh, nullptr, buf);
    else
        gemm_body<2>(Xvh, Xvl, Wvh, Wvl, bv, nullptr, nullptr, Vth, nullptr, buf);
}

__global__ __launch_bounds__(256) void gemm_out(
        const ushort_t* __restrict__ AOh, const ushort_t* __restrict__ AOl,
        const ushort_t* __restrict__ Wth, const ushort_t* __restrict__ Wtl,
        const float* __restrict__ bias, float* __restrict__ OutF)
{
    __shared__ ushort_t buf[2 * 16384];
    gemm_body<3>(AOh, AOl, Wth, Wtl, bias, nullptr, OutF, nullptr, nullptr, buf);
}

// ---------------------------------------------------------------------------
// Fused attention, 512 threads / 8 waves; wave owns 256 score columns.
// Q arrives pre-scaled by 0.15625. Diag boost lives in one wave's span.
// Phase 2: exchange + binary key bisection. wr1 is issued AFTER half-0's
// shuffle reduce (DS in-order!) but BEFORE the DS-free bisect loop, so the
// writes drain under the search. Output written as split bf16 for gemm_out.
// ---------------------------------------------------------------------------
__global__ __launch_bounds__(512, 4) void attn_kernel(
        const ushort_t* __restrict__ Qh, const ushort_t* __restrict__ Ql,
        const ushort_t* __restrict__ Khi, const ushort_t* __restrict__ Vth,
        ushort_t* __restrict__ AOh, ushort_t* __restrict__ AOl)
{
    __shared__ __align__(16) char uni[65536];
    __shared__ float wsums[8][16];
    __shared__ float thr16[16];

    const int tid  = threadIdx.x;
    const int lane = tid & 63;
    const int wave = tid >> 6;
    const int qd   = lane >> 4;
    const int c16  = lane & 15;
    const unsigned Bx = blockIdx.x;
    const int xcd  = Bx & 7;
    const int qq   = Bx >> 3;
    const int tile = qq & 127;
    const int bh   = (qq >> 7) * 8 + xcd;
    const int t0   = tile * QT;
    const int wbase = wave * 256;

    // ---- Q fragments (pre-split hi/lo, pre-scaled) ----
    bf16x8 qh[2], ql[2];
    {
        const size_t qbase = ((size_t)bh * SS + t0 + c16) * DH;
        #pragma unroll
        for (int kc = 0; kc < 2; ++kc){
            qh[kc] = *(const bf16x8*)&Qh[qbase + kc*32 + qd*8];
            ql[kc] = *(const bf16x8*)&Ql[qbase + kc*32 + qd*8];
        }
    }

    // ---- phase 1: scores (K hi-only, Q split) ----
    f32x4 acc[16];
    const ushort_t* Kh = Khi + (size_t)bh * SS * DH;
    #pragma unroll
    for (int t = 0; t < 16; ++t){
        f32x4 a = {0.f, 0.f, 0.f, 0.f};
        const int srow = wbase + t*16 + c16;
        const ushort_t* kp = Kh + (size_t)srow * DH + qd*8;
        #pragma unroll
        for (int kc = 0; kc < 2; ++kc){
            bf16x8 kh = *(const bf16x8*)(kp + kc*32);
            a = __builtin_amdgcn_mfma_f32_16x16x32_bf16(qh[kc], kh, a, 0, 0, 0);
            a = __builtin_amdgcn_mfma_f32_16x16x32_bf16(ql[kc], kh, a, 0, 0, 0);
        }
        acc[t] = a;
    }

    // ---- diag boost: the 16 diag columns live in exactly one wave ----
    if (wave == (t0 >> 8)){
        #pragma unroll
        for (int t = 0; t < 16; ++t){
            const int colg = wbase + t*16 + c16;
            #pragma unroll
            for (int r = 0; r < 4; ++r)
                if (colg == t0 + qd*4 + r) acc[t][r] *= 1.15f;
        }
    }

    // ---- phase 2: exact top-k thresholds ----
    float* ex = (float*)uni;   // 8 rows x 2048 fp32
    if (qd < 2){               // write half 0 (rows 0..7)
        const int rl = (qd & 1) * 4;
        #pragma unroll
        for (int t = 0; t < 16; ++t)
            #pragma unroll
            for (int r = 0; r < 4; ++r)
                ex[(rl + r) * SS + wbase + t*16 + c16] = acc[t][r];
    }
    __syncthreads();                      // B1: wr0 visible
    float cand[32];
    #pragma unroll
    for (int j = 0; j < 32; ++j)
        cand[j] = ex[wave * SS + lane + 64*j];
    __syncthreads();                      // B2: all rd0 complete block-wide
    {
        float mn, mx;
        wave_minmax(cand, mn, mx);        // DS shuffles BEFORE wr1 is queued
        if (qd >= 2){                     // write half 1; drains under bisect
            const int rl = (qd & 1) * 4;
            #pragma unroll
            for (int t = 0; t < 16; ++t)
                #pragma unroll
                for (int r = 0; r < 4; ++r)
                    ex[(rl + r) * SS + wbase + t*16 + c16] = acc[t][r];
        }
        const float th0 = bisect_thresh(cand, mn, mx);   // DS-free
        if (lane == 0) thr16[wave] = th0;
    }
    __syncthreads();                      // B3: wr1 visible
    #pragma unroll
    for (int j = 0; j < 32; ++j)
        cand[j] = ex[wave * SS + lane + 64*j];
    {
        float mn, mx;
        wave_minmax(cand, mn, mx);
        const float th1 = bisect_thresh(cand, mn, mx);
        if (lane == 0) thr16[8 + wave] = th1;
    }
    __syncthreads();                      // B4: rd1 done + thr16 visible

    // ---- phase 3: boost folded into exp arg + row sums ----
    float thr[4];
    #pragma unroll
    for (int r = 0; r < 4; ++r) thr[r] = thr16[qd*4 + r];
    float psum[4] = {0.f, 0.f, 0.f, 0.f};
    #pragma unroll
    for (int t = 0; t < 16; ++t){
        #pragma unroll
        for (int r = 0; r < 4; ++r){
            const float s = acc[t][r];
            const float m = (s >= thr[r]) ? 1.15f : 1.0f;
            const float e = __expf(s * m);
            acc[t][r] = e;
            psum[r] += e;
        }
    }
    #pragma unroll
    for (int off = 1; off <= 8; off <<= 1){
        #pragma unroll
        for (int r = 0; r < 4; ++r) psum[r] += __shfl_xor(psum[r], off, 64);
    }
    if (c16 == 0){
        #pragma unroll
        for (int r = 0; r < 4; ++r) wsums[wave][qd*4 + r] = psum[r];
    }
    __syncthreads();
    float pinv[4];
    #pragma unroll
    for (int r = 0; r < 4; ++r){
        const int row = qd*4 + r;
        float s = 0.f;
        #pragma unroll
        for (int w = 0; w < 8; ++w) s += wsums[w][row];
        pinv[r] = 1.f / s;
    }

    // ---- phase 4: O = P @ V (two 128-col halves per wave) ----
    // oacc is initialized AFTER half-0's P-writes so acc[0..7]'s registers
    // are dead by then (register-pressure trim -> occupancy).
    const ushort_t* Vh = Vth + (size_t)bh * DH * SS;
    ushort_t* pw = (ushort_t*)uni + wave * (QT * PST);   // per-wave region

    // half 0 P-writes (consume acc[0..7])
    #pragma unroll
    for (int tt = 0; tt < 8; ++tt)
        #pragma unroll
        for (int r = 0; r < 4; ++r)
            pw[(qd*4 + r) * PST + tt*16 + c16] = f2bf(acc[tt][r] * pinv[r]);

    f32x4 oacc[4];
    #pragma unroll
    for (int dt = 0; dt < 4; ++dt) oacc[dt] = (f32x4){0.f, 0.f, 0.f, 0.f};

    // per-wave region: same-wave ds_write -> ds_read, no barrier needed
    #pragma unroll
    for (int kc = 0; kc < 4; ++kc){
        bf16x8 pf = *(const bf16x8*)&pw[c16 * PST + kc*32 + qd*8];
        const int sbase = wbase + kc*32 + qd*8;
        #pragma unroll
        for (int dt = 0; dt < 4; ++dt){
            const int d = dt*16 + c16;
            bf16x8 vh = *(const bf16x8*)(Vh + (size_t)d * SS + sbase);
            oacc[dt] = __builtin_amdgcn_mfma_f32_16x16x32_bf16(pf, vh, oacc[dt], 0, 0, 0);
        }
    }
    // half 1 P-writes (consume acc[8..15])
    #pragma unroll
    for (int tt = 0; tt < 8; ++tt)
        #pragma unroll
        for (int r = 0; r < 4; ++r)
            pw[(qd*4 + r) * PST + tt*16 + c16] = f2bf(acc[8 + tt][r] * pinv[r]);
    #pragma unroll
    for (int kc = 0; kc < 4; ++kc){
        bf16x8 pf = *(const bf16x8*)&pw[c16 * PST + kc*32 + qd*8];
        const int sbase = wbase + 128 + kc*32 + qd*8;
        #pragma unroll
        for (int dt = 0; dt < 4; ++dt){
            const int d = dt*16 + c16;
            bf16x8 vh = *(const bf16x8*)(Vh + (size_t)d * SS + sbase);
            oacc[dt] = __builtin_amdgcn_mfma_f32_16x16x32_bf16(pf, vh, oacc[dt], 0, 0, 0);
        }
    }

    // ---- cross-wave O reduction + split bf16 store ----
    __syncthreads();   // all probs reads done before red overwrites the union
    float* red = (float*)uni;   // 8 x 16 x 65
    #pragma unroll
    for (int dt = 0; dt < 4; ++dt)
        #pragma unroll
        for (int r = 0; r < 4; ++r)
            red[(wave*16 + qd*4 + r) * 65 + dt*16 + c16] = oacc[dt][r];
    __syncthreads();

    const int b = bh >> 4, h = bh & 15;
    {
        const int r  = tid >> 5;           // 0..15
        const int c2 = (tid & 31) * 2;     // 0,2,..,62
        float s0 = 0.f, s1 = 0.f;
        #pragma unroll
        for (int w = 0; w < 8; ++w){
            s0 += red[(w*16 + r) * 65 + c2];
            s1 += red[(w*16 + r) * 65 + c2 + 1];
        }
        const size_t o = ((size_t)b * SS + t0 + r) * EE + h*DH + c2;
        ushort2 hv, lv;
        hv.x = f2bf(s0); lv.x = f2bf(s0 - bf2f(hv.x));
        hv.y = f2bf(s1); lv.y = f2bf(s1 - bf2f(hv.y));
        *(ushort2*)&AOh[o] = hv;
        *(ushort2*)&AOl[o] = lv;
    }
}

// ---------------------------------------------------------------------------
extern "C" void kernel_launch(void* const* d_in, const int* in_sizes, int n_in,
                              void* d_out, int out_size, void* d_ws, size_t ws_size,
                              hipStream_t stream)
{
    const float* query = (const float*)d_in[0];
    const float* key   = (const float*)d_in[1];
    const float* value = (const float*)d_in[2];
    const float* Wq    = (const float*)d_in[3];
    const float* bq    = (const float*)d_in[4];
    const float* Wk    = (const float*)d_in[5];
    const float* bk    = (const float*)d_in[6];
    const float* Wv    = (const float*)d_in[7];
    const float* bv    = (const float*)d_in[8];
    const float* Wo    = (const float*)d_in[9];
    const float* bo    = (const float*)d_in[10];
    const float* ts    = (const float*)d_in[11];
    float* out = (float*)d_out;
    char* w = (char*)d_ws;

    const size_t MB = 1u << 20;
    // 0-32: attention operand buffers (outputs of gemm_qkv)
    ushort_t* Qh  = (ushort_t*)(w + 0 * MB);
    ushort_t* Ql  = (ushort_t*)(w + 8 * MB);
    ushort_t* Kh  = (ushort_t*)(w + 16 * MB);
    ushort_t* Vth = (ushort_t*)(w + 24 * MB);
    // 32-48: converted weights (2 MB each)
    ushort_t* Wqh = (ushort_t*)(w + 32 * MB);
    ushort_t* Wql = (ushort_t*)(w + 34 * MB);
    ushort_t* Wkh = (ushort_t*)(w + 36 * MB);
    ushort_t* Wkl = (ushort_t*)(w + 38 * MB);
    ushort_t* Wvh = (ushort_t*)(w + 40 * MB);
    ushort_t* Wvl = (ushort_t*)(w + 42 * MB);
    ushort_t* Woh = (ushort_t*)(w + 44 * MB);
    ushort_t* Wol = (ushort_t*)(w + 46 * MB);
    // 48-96: pre-split activations (8 MB each)
    ushort_t* Xqh = (ushort_t*)(w + 48 * MB);
    ushort_t* Xql = (ushort_t*)(w + 56 * MB);
    ushort_t* Xkh = (ushort_t*)(w + 64 * MB);
    ushort_t* Xkl = (ushort_t*)(w + 72 * MB);
    ushort_t* Xvh = (ushort_t*)(w + 80 * MB);
    ushort_t* Xvl = (ushort_t*)(w + 88 * MB);
    // attn output overlays the Xq region (dead after gemm_qkv, stream-ordered)
    ushort_t* AOh = (ushort_t*)(w + 48 * MB);
    ushort_t* AOl = (ushort_t*)(w + 56 * MB);

    CvtArgs ca;
    ca.W[0] = Wq;  ca.W[1] = Wk;  ca.W[2] = Wv;  ca.W[3] = Wo;
    ca.H[0] = Wqh; ca.H[1] = Wkh; ca.H[2] = Wvh; ca.H[3] = Woh;
    ca.L[0] = Wql; ca.L[1] = Wkl; ca.L[2] = Wvl; ca.L[3] = Wol;

    CvtX cx;
    cx.X[0] = query; cx.X[1] = key; cx.X[2] = value;
    cx.H[0] = Xqh;   cx.H[1] = Xkh; cx.H[2] = Xvh;
    cx.L[0] = Xql;   cx.L[1] = Xkl; cx.L[2] = Xvl;

    hipLaunchKernelGGL(convert_wt4, dim3(16, 16, 4), dim3(256), 0, stream, ca);
    hipLaunchKernelGGL(convert_x3, dim3(2048, 1, 3), dim3(256), 0, stream, cx);
    hipLaunchKernelGGL(gemm_qkv, dim3(8, 32, 3), dim3(256), 0, stream,
                       Xqh, Xql, Xkh, Xkl, Xvh, Xvl,
                       Wqh, Wql, Wkh, Wkl, Wvh, Wvl,
                       bq, bk, bv, ts, Qh, Ql, Kh, Vth);
    hipLaunchKernelGGL(attn_kernel, dim3(BB * HH * (SS / QT)), dim3(512), 0, stream,
                       Qh, Ql, Kh, Vth, AOh, AOl);
    hipLaunchKernelGGL(gemm_out, dim3(8, 32), dim3(256), 0, stream,
                       AOh, AOl, Woh, Wol, bo, out);
}